// Round 1
// baseline (19.920 us; speedup 1.0000x reference)
//
#include <hip/hip_runtime.h>

// TaylorLayer: B=262144, n=8 features, q=1, exp_order=2 -> monomials deg 1..3
// T = 8 + 36 + 120 = 164, N_OUT = 8.
//
// Ordering (matches reference recursion):
//   t in [0,8):    x_j                       (t = j)
//   t in [8,44):   x_j*x_k, j<=k, j-major    (t = 8 + idx2(j,k))
//   t in [44,164): x_j*x_a*x_b, j<=a<=b      (j-major, then a, then b)
//
// One thread per batch element; fully unrolled so every W index is a
// compile-time constant -> uniform address -> scalar loads (SGPR operand
// into v_fma). Monomials deg-2 cached in a statically-indexed reg array.

static constexpr int NOUT = 8;
static constexpr int TEXP = 164;

__device__ __forceinline__ float relu(float v) { return fmaxf(v, 0.0f); }

__global__ __launch_bounds__(256) void taylor_kernel(
    const float* __restrict__ x, const float* __restrict__ W,
    const float* __restrict__ b, float* __restrict__ out, int n) {
  int i = blockIdx.x * blockDim.x + threadIdx.x;
  if (i >= n) return;

  // x layout [B, 8, 1] -> 8 contiguous floats per element
  float4 xa = reinterpret_cast<const float4*>(x)[i * 2 + 0];
  float4 xb = reinterpret_cast<const float4*>(x)[i * 2 + 1];
  float xv[8] = {xa.x, xa.y, xa.z, xa.w, xb.x, xb.y, xb.z, xb.w};

  float acc[NOUT];
#pragma unroll
  for (int o = 0; o < NOUT; ++o) acc[o] = b[o];  // b is [8,1]

  int t = 0;

  // ---- degree 1 ----
#pragma unroll
  for (int j = 0; j < 8; ++j) {
    float m = xv[j];
#pragma unroll
    for (int o = 0; o < NOUT; ++o) acc[o] = fmaf(W[o * TEXP + t], m, acc[o]);
    ++t;
  }

  // ---- degree 2 (cache for degree 3) ----
  float d2[36];
  int p = 0;
#pragma unroll
  for (int j = 0; j < 8; ++j) {
#pragma unroll
    for (int k = j; k < 8; ++k) {
      float m = xv[j] * xv[k];
      d2[p] = m;
      ++p;
#pragma unroll
      for (int o = 0; o < NOUT; ++o) acc[o] = fmaf(W[o * TEXP + t], m, acc[o]);
      ++t;
    }
  }

  // ---- degree 3: x_j * d2[(a,b)] for j<=a<=b ----
#pragma unroll
  for (int j = 0; j < 8; ++j) {
#pragma unroll
    for (int a = j; a < 8; ++a) {
      int rowstart = a * 8 - a * (a - 1) / 2 - a;  // idx2(a,b) = rowstart + b
#pragma unroll
      for (int bb = a; bb < 8; ++bb) {
        float m = xv[j] * d2[rowstart + bb];
#pragma unroll
        for (int o = 0; o < NOUT; ++o) acc[o] = fmaf(W[o * TEXP + t], m, acc[o]);
        ++t;
      }
    }
  }

  float4 o0 = make_float4(relu(acc[0]), relu(acc[1]), relu(acc[2]), relu(acc[3]));
  float4 o1 = make_float4(relu(acc[4]), relu(acc[5]), relu(acc[6]), relu(acc[7]));
  reinterpret_cast<float4*>(out)[i * 2 + 0] = o0;
  reinterpret_cast<float4*>(out)[i * 2 + 1] = o1;
}

extern "C" void kernel_launch(void* const* d_in, const int* in_sizes, int n_in,
                              void* d_out, int out_size, void* d_ws, size_t ws_size,
                              hipStream_t stream) {
  const float* x = (const float*)d_in[0];   // [262144, 8, 1]
  const float* W = (const float*)d_in[1];   // [8, 164]
  const float* b = (const float*)d_in[2];   // [8, 1]
  float* out = (float*)d_out;               // [262144, 8, 1]

  int n = in_sizes[0] / 8;  // batch elements
  int block = 256;
  int grid = (n + block - 1) / block;
  taylor_kernel<<<grid, block, 0, stream>>>(x, W, b, out, n);
}